// Round 1
// baseline (787.073 us; speedup 1.0000x reference)
//
#include <hip/hip_runtime.h>
#include <hip/hip_bf16.h>
#include <math.h>

typedef __bf16 bf16;
typedef bf16 bf16x8 __attribute__((ext_vector_type(8)));
typedef float f32x4 __attribute__((ext_vector_type(4)));

#define B_   2
#define N_   2048
#define D_   1024
#define H_   16
#define HC_  8
#define HID_ 4096
#define M_   (B_*N_)   // 4096 rows in all big GEMMs

// ============================================================
// Stage A: time-conditioning MLP (GEMV, B=2 rows)
// ============================================================
__global__ __launch_bounds__(256) void emb_kernel(const float* __restrict__ tin,
                                                  float* __restrict__ emb) {
  int idx = blockIdx.x * 256 + threadIdx.x;   // 0..8191
  int b = idx >> 12, p = idx & 4095;
  float tv = tin[b];
  int half = p & 2047;
  float freq = expf(-logf(10000.f) * (float)half * (1.f / 2048.f));
  float arg = tv * freq;
  emb[idx] = (p < 2048) ? cosf(arg) : sinf(arg);
}

// W: (4096 x 4096) row-major (fin,fout). grid (8 jblocks, 32 kchunks), 256 thr.
// part[(kc*2+b)*4096 + j] partial sums.
__global__ __launch_bounds__(256) void gemv_kernel(const float* __restrict__ x,
                                                   const float* __restrict__ W,
                                                   float* __restrict__ part) {
  __shared__ float xs[2][128];
  int t = threadIdx.x;
  int j0 = blockIdx.x * 512;
  int k0 = blockIdx.y * 128;
  if (t < 128) xs[0][t] = x[k0 + t];
  else         xs[1][t - 128] = x[4096 + k0 + (t - 128)];
  __syncthreads();
  float a00 = 0.f, a01 = 0.f, a10 = 0.f, a11 = 0.f;
  int j = j0 + t * 2;
  #pragma unroll 8
  for (int k = 0; k < 128; k++) {
    float2 wv = *(const float2*)(W + (size_t)(k0 + k) * 4096 + j);
    float x0 = xs[0][k], x1 = xs[1][k];
    a00 += x0 * wv.x; a01 += x0 * wv.y;
    a10 += x1 * wv.x; a11 += x1 * wv.y;
  }
  *(float2*)(part + (size_t)(blockIdx.y * 2 + 0) * 4096 + j) = make_float2(a00, a01);
  *(float2*)(part + (size_t)(blockIdx.y * 2 + 1) * 4096 + j) = make_float2(a10, a11);
}

__global__ __launch_bounds__(256) void gemv_reduce_kernel(const float* __restrict__ part,
                                                          const float* __restrict__ bias,
                                                          float* __restrict__ y, int act) {
  int idx = blockIdx.x * 256 + threadIdx.x;   // 0..8191
  int b = idx >> 12, j = idx & 4095;
  float s = bias[j];
  #pragma unroll
  for (int kc = 0; kc < 32; kc++) s += part[(size_t)(kc * 2 + b) * 4096 + j];
  if (act) s = s / (1.f + expf(-s));          // silu
  y[idx] = s;
}

// derived per-(b,d) vectors: exp(lg), gate*gamma
__global__ __launch_bounds__(256) void postA_kernel(const float* __restrict__ avec,
                                                    const float* __restrict__ cvec,
                                                    const float* __restrict__ g1,
                                                    const float* __restrict__ g2,
                                                    float* __restrict__ sca, float* __restrict__ scc,
                                                    float* __restrict__ agv, float* __restrict__ cgv) {
  int idx = blockIdx.x * 256 + threadIdx.x;   // 0..2047
  int b = idx >> 10, d = idx & 1023;
  sca[idx] = expf(avec[b * 4096 + 3072 + d]);
  scc[idx] = expf(cvec[b * 4096 + 3072 + d]);
  agv[idx] = avec[b * 4096 + 2048 + d] * g1[d];
  cgv[idx] = cvec[b * 4096 + 2048 + d] * g2[d];
}

// ============================================================
// Weight fp32 (K x N) -> bf16 transposed (N x K)
// ============================================================
__global__ __launch_bounds__(256) void wtconv_kernel(const float* __restrict__ W,
                                                     bf16* __restrict__ Wt) {
  __shared__ float tile[32][33];
  int t = threadIdx.x;
  int i = t >> 5, j = t & 31;
  int n0 = blockIdx.x * 32, k0 = blockIdx.y * 32;
  #pragma unroll
  for (int u = 0; u < 4; u++) {
    int k = i + u * 8;
    tile[k][j] = W[(size_t)(k0 + k) * 1024 + n0 + j];
  }
  __syncthreads();
  #pragma unroll
  for (int u = 0; u < 4; u++) {
    int n = i + u * 8;
    Wt[(size_t)(n0 + n) * 1024 + k0 + j] = (bf16)tile[j][n];
  }
}

// ============================================================
// LayerNorm + modulate -> bf16
// ============================================================
__global__ __launch_bounds__(256) void ln_mod_kernel(const float* __restrict__ xin,
                                                     const float* __restrict__ nsc,
                                                     const float* __restrict__ nbi,
                                                     const float* __restrict__ mod, // (B,4096): shift@0, scale@1024
                                                     bf16* __restrict__ outp) {
  int row = blockIdx.x;              // 0..4095
  int b = row >> 11;
  int t = threadIdx.x;
  const float* xr = xin + (size_t)row * 1024;
  float v[4], s = 0.f, ss = 0.f;
  #pragma unroll
  for (int u = 0; u < 4; u++) { v[u] = xr[t + u * 256]; s += v[u]; ss += v[u] * v[u]; }
  #pragma unroll
  for (int off = 1; off < 64; off <<= 1) { s += __shfl_xor(s, off, 64); ss += __shfl_xor(ss, off, 64); }
  __shared__ float sb[4], ssb[4];
  if ((t & 63) == 0) { sb[t >> 6] = s; ssb[t >> 6] = ss; }
  __syncthreads();
  s = sb[0] + sb[1] + sb[2] + sb[3];
  ss = ssb[0] + ssb[1] + ssb[2] + ssb[3];
  float mu = s * (1.f / 1024.f);
  float var = ss * (1.f / 1024.f) - mu * mu;
  float rs = rsqrtf(var + 1e-6f);
  const float* shv = mod + b * 4096;
  const float* scv = mod + b * 4096 + 1024;
  #pragma unroll
  for (int u = 0; u < 4; u++) {
    int d = t + u * 256;
    float y = (v[u] - mu) * rs * nsc[d] + nbi[d];
    outp[(size_t)row * 1024 + d] = (bf16)(y * (1.f + scv[d]) + shv[d]);
  }
}

// ============================================================
// bf16 MFMA GEMM: C(4096x1024) = A(4096x1024) * W, Wt given as (N x K) bf16.
// 128x128 tile, BK=64, 2x2 waves, 4x4 16x16x32 tiles per wave.
// MODE: 0 plain bf16 out (B,N,D); 1 colscale bf16 (B,N,D);
//       2 colscale bf16 -> (B,HC,128,N); 3 bf16 -> (B,H,64,N);
//       4 fp32 out = resid + acc*gate  (B,N,D)
// ============================================================
template <int MODE>
__global__ __launch_bounds__(256) void gemm_kernel(const bf16* __restrict__ A,
                                                   const bf16* __restrict__ Wt,
                                                   const float* __restrict__ scale,
                                                   const float* __restrict__ resid,
                                                   void* __restrict__ outp) {
  const int K = 1024;
  __shared__ bf16 As[128 * 72];
  __shared__ bf16 Bs[128 * 72];
  int m0 = blockIdx.x * 128;
  int n0 = blockIdx.y * 128;
  int t = threadIdx.x, lane = t & 63, wid = t >> 6;
  int wy = wid >> 1, wx = wid & 1;
  int ml = lane & 15, kq = (lane >> 4) * 8, rq = (lane >> 4) * 4;

  f32x4 acc[4][4] = {};
  for (int k0 = 0; k0 < K; k0 += 64) {
    __syncthreads();
    #pragma unroll
    for (int u = 0; u < 4; u++) {
      int idx = u * 256 + t;              // 1024 units of 16B
      int r = idx >> 3, seg = (idx & 7) * 8;
      *(uint4*)(As + r * 72 + seg) = *(const uint4*)(A  + (size_t)(m0 + r) * K + k0 + seg);
      *(uint4*)(Bs + r * 72 + seg) = *(const uint4*)(Wt + (size_t)(n0 + r) * K + k0 + seg);
    }
    __syncthreads();
    #pragma unroll
    for (int ks = 0; ks < 2; ks++) {
      bf16x8 af[4], bfv[4];
      #pragma unroll
      for (int i = 0; i < 4; i++)
        af[i] = *(const bf16x8*)(As + (wy * 64 + i * 16 + ml) * 72 + ks * 32 + kq);
      #pragma unroll
      for (int j = 0; j < 4; j++)
        bfv[j] = *(const bf16x8*)(Bs + (wx * 64 + j * 16 + ml) * 72 + ks * 32 + kq);
      #pragma unroll
      for (int i = 0; i < 4; i++)
        #pragma unroll
        for (int j = 0; j < 4; j++)
          acc[i][j] = __builtin_amdgcn_mfma_f32_16x16x32_bf16(af[i], bfv[j], acc[i][j], 0, 0, 0);
    }
  }
  // epilogue
  #pragma unroll
  for (int i = 0; i < 4; i++) {
    #pragma unroll
    for (int j = 0; j < 4; j++) {
      int col = n0 + wx * 64 + j * 16 + ml;
      #pragma unroll
      for (int r = 0; r < 4; r++) {
        int row = m0 + wy * 64 + i * 16 + rq + r;
        int b = row >> 11, n = row & 2047;
        float val = acc[i][j][r];
        if constexpr (MODE == 0) {
          ((bf16*)outp)[(size_t)row * 1024 + col] = (bf16)val;
        } else if constexpr (MODE == 1) {
          val *= scale[b * 1024 + col];
          ((bf16*)outp)[(size_t)row * 1024 + col] = (bf16)val;
        } else if constexpr (MODE == 2) {
          val *= scale[b * 1024 + col];
          int hc = col >> 7, c = col & 127;
          ((bf16*)outp)[((size_t)((b * 8 + hc) * 128 + c)) * 2048 + n] = (bf16)val;
        } else if constexpr (MODE == 3) {
          int hh = col >> 6, dh = col & 63;
          ((bf16*)outp)[((size_t)((b * 16 + hh) * 64 + dh)) * 2048 + n] = (bf16)val;
        } else {
          float g = scale[b * 1024 + col];
          ((float*)outp)[(size_t)row * 1024 + col] =
              resid[(size_t)row * 1024 + col] + val * g;
        }
      }
    }
  }
}

// ============================================================
// phi (doob) + per-head q2 + e = phi - q2
// ============================================================
__global__ __launch_bounds__(256) void phiq2_kernel(const bf16* __restrict__ x1,
                                                    const bf16* __restrict__ qk,
                                                    const float* __restrict__ doobw,
                                                    const float* __restrict__ doobb,
                                                    float* __restrict__ q2buf,
                                                    float* __restrict__ ebuf) {
  int row = blockIdx.x;              // b*2048+n
  int b = row >> 11, n = row & 2047;
  int t = threadIdx.x;
  const bf16* xr = x1 + (size_t)row * 1024;
  const bf16* qr = qk + (size_t)row * 1024;
  float ph = 0.f;
  #pragma unroll
  for (int u = 0; u < 4; u++) { int d = t + u * 256; ph += (float)xr[d] * doobw[d]; }
  #pragma unroll
  for (int off = 1; off < 64; off <<= 1) ph += __shfl_xor(ph, off, 64);
  __shared__ float pb[4];
  __shared__ float q2s[16][17];
  if ((t & 63) == 0) pb[t >> 6] = ph;
  {
    int h = t >> 4, i0 = (t & 15) * 4;
    float q = 0.f;
    #pragma unroll
    for (int u = 0; u < 4; u++) { float qv = (float)qr[h * 64 + i0 + u]; q += qv * qv; }
    q2s[h][t & 15] = q;
  }
  __syncthreads();
  float phi = pb[0] + pb[1] + pb[2] + pb[3] + doobb[0];
  if (t < 16) {
    float q2 = 0.f;
    #pragma unroll
    for (int u = 0; u < 16; u++) q2 += q2s[t][u];
    q2buf[(size_t)(b * 16 + t) * 2048 + n] = q2;
    ebuf [(size_t)(b * 16 + t) * 2048 + n] = phi - q2;
  }
}

// ============================================================
// Flash attention (token): tied Q=K, logits = 2*S - q2[m] + e[n]
// grid (16 mtiles, 32 bh); block 256 = 4 waves; 128 Q-rows/block, 64-wide chunks
// ============================================================
__global__ __launch_bounds__(256) void flash_kernel(const bf16* __restrict__ qk,  // (B,N,D)
                                                    const bf16* __restrict__ vt,  // (B,H,64,N)
                                                    const float* __restrict__ q2buf,
                                                    const float* __restrict__ ebuf,
                                                    bf16* __restrict__ wout) {    // (B,N,D)
  int mt = blockIdx.x, bh = blockIdx.y;
  int b = bh >> 4, h = bh & 15;
  int m0 = mt * 128;
  int t = threadIdx.x, lane = t & 63, w = t >> 6;
  int ml = lane & 15, kq = (lane >> 4) * 8, rq = (lane >> 4) * 4;

  __shared__ bf16 Qs[128 * 72];
  __shared__ bf16 Ks[64 * 72];
  __shared__ bf16 Vs[64 * 72];   // Vs[dh][n]
  __shared__ bf16 Ps[128 * 72];

  #pragma unroll
  for (int u = 0; u < 4; u++) {                      // Q: 128 rows x 8 x 16B
    int idx = u * 256 + t;
    int r = idx >> 3, seg = (idx & 7) * 8;
    *(uint4*)(Qs + r * 72 + seg) =
        *(const uint4*)(qk + (size_t)(b * 2048 + m0 + r) * 1024 + h * 64 + seg);
  }
  float rmax[2][4], rsum[2][4], q2r[2][4];
  const float* q2p = q2buf + (size_t)bh * 2048 + m0;
  #pragma unroll
  for (int i = 0; i < 2; i++)
    #pragma unroll
    for (int r = 0; r < 4; r++) {
      q2r[i][r] = q2p[w * 32 + i * 16 + rq + r];
      rmax[i][r] = -1e30f; rsum[i][r] = 0.f;
    }
  f32x4 oacc[2][4] = {};
  const float* ep = ebuf + (size_t)bh * 2048;

  for (int nc = 0; nc < 32; nc++) {
    int n0 = nc * 64;
    __syncthreads();
    #pragma unroll
    for (int u = 0; u < 2; u++) {                    // K chunk: 64 rows x 8 x 16B
      int idx = u * 256 + t;
      int r = idx >> 3, seg = (idx & 7) * 8;
      *(uint4*)(Ks + r * 72 + seg) =
          *(const uint4*)(qk + (size_t)(b * 2048 + n0 + r) * 1024 + h * 64 + seg);
      *(uint4*)(Vs + r * 72 + seg) =
          *(const uint4*)(vt + (size_t)(bh * 64 + r) * 2048 + n0 + seg);
    }
    __syncthreads();

    f32x4 sacc[2][4] = {};
    #pragma unroll
    for (int ks = 0; ks < 2; ks++) {
      bf16x8 qa[2], kb[4];
      #pragma unroll
      for (int i = 0; i < 2; i++)
        qa[i] = *(const bf16x8*)(Qs + (w * 32 + i * 16 + ml) * 72 + ks * 32 + kq);
      #pragma unroll
      for (int j = 0; j < 4; j++)
        kb[j] = *(const bf16x8*)(Ks + (j * 16 + ml) * 72 + ks * 32 + kq);
      #pragma unroll
      for (int i = 0; i < 2; i++)
        #pragma unroll
        for (int j = 0; j < 4; j++)
          sacc[i][j] = __builtin_amdgcn_mfma_f32_16x16x32_bf16(qa[i], kb[j], sacc[i][j], 0, 0, 0);
    }

    float ej[4];
    #pragma unroll
    for (int j = 0; j < 4; j++) ej[j] = ep[n0 + j * 16 + ml];
    float alpha[2][4];
    #pragma unroll
    for (int i = 0; i < 2; i++) {
      #pragma unroll
      for (int r = 0; r < 4; r++) {
        float lv[4];
        #pragma unroll
        for (int j = 0; j < 4; j++) lv[j] = 2.f * sacc[i][j][r] - q2r[i][r] + ej[j];
        float cm = fmaxf(fmaxf(lv[0], lv[1]), fmaxf(lv[2], lv[3]));
        cm = fmaxf(cm, __shfl_xor(cm, 1, 64));
        cm = fmaxf(cm, __shfl_xor(cm, 2, 64));
        cm = fmaxf(cm, __shfl_xor(cm, 4, 64));
        cm = fmaxf(cm, __shfl_xor(cm, 8, 64));
        float nm = fmaxf(rmax[i][r], cm);
        float al = expf(rmax[i][r] - nm);
        float psum = 0.f;
        int prow = (w * 32 + i * 16 + rq + r) * 72;
        #pragma unroll
        for (int j = 0; j < 4; j++) {
          float p = expf(lv[j] - nm);
          psum += p;
          Ps[prow + j * 16 + ml] = (bf16)p;
        }
        psum += __shfl_xor(psum, 1, 64);
        psum += __shfl_xor(psum, 2, 64);
        psum += __shfl_xor(psum, 4, 64);
        psum += __shfl_xor(psum, 8, 64);
        rsum[i][r] = rsum[i][r] * al + psum;
        rmax[i][r] = nm;
        alpha[i][r] = al;
      }
    }
    #pragma unroll
    for (int i = 0; i < 2; i++)
      #pragma unroll
      for (int jd = 0; jd < 4; jd++)
        #pragma unroll
        for (int r = 0; r < 4; r++) oacc[i][jd][r] *= alpha[i][r];
    __syncthreads();
    #pragma unroll
    for (int ks = 0; ks < 2; ks++) {
      bf16x8 pa[2], vb[4];
      #pragma unroll
      for (int i = 0; i < 2; i++)
        pa[i] = *(const bf16x8*)(Ps + (w * 32 + i * 16 + ml) * 72 + ks * 32 + kq);
      #pragma unroll
      for (int jd = 0; jd < 4; jd++)
        vb[jd] = *(const bf16x8*)(Vs + (jd * 16 + ml) * 72 + ks * 32 + kq);
      #pragma unroll
      for (int i = 0; i < 2; i++)
        #pragma unroll
        for (int jd = 0; jd < 4; jd++)
          oacc[i][jd] = __builtin_amdgcn_mfma_f32_16x16x32_bf16(pa[i], vb[jd], oacc[i][jd], 0, 0, 0);
    }
  }
  #pragma unroll
  for (int i = 0; i < 2; i++)
    #pragma unroll
    for (int jd = 0; jd < 4; jd++)
      #pragma unroll
      for (int r = 0; r < 4; r++) {
        int row = w * 32 + i * 16 + rq + r;
        wout[(size_t)(b * 2048 + m0 + row) * 1024 + h * 64 + jd * 16 + ml] =
            (bf16)(oacc[i][jd][r] / rsum[i][r]);
      }
}

// ============================================================
// Channel attention
// ============================================================
// Gram: dotc[bh][c][d] = sum_n q[c][n] q[d][n];  qkct: (B*HC, 128, 2048) bf16
__global__ __launch_bounds__(256) void gram_kernel(const bf16* __restrict__ qkct,
                                                   float* __restrict__ dotc) {
  int bh = blockIdx.x;
  const bf16* Q = qkct + (size_t)bh * 128 * 2048;
  __shared__ bf16 Ts[128 * 40];
  int t = threadIdx.x, lane = t & 63, w = t >> 6;
  int ml = lane & 15, kq = (lane >> 4) * 8, rq = (lane >> 4) * 4;
  f32x4 acc[2][8] = {};
  for (int k0 = 0; k0 < 2048; k0 += 32) {
    __syncthreads();
    #pragma unroll
    for (int u = 0; u < 2; u++) {
      int idx = u * 256 + t;                 // 512 units: 128 rows x 4 x 16B
      int r = idx >> 2, seg = (idx & 3) * 8;
      *(uint4*)(Ts + r * 40 + seg) = *(const uint4*)(Q + (size_t)r * 2048 + k0 + seg);
    }
    __syncthreads();
    bf16x8 afr[2], bfr[8];
    #pragma unroll
    for (int i = 0; i < 2; i++) afr[i] = *(const bf16x8*)(Ts + (w * 32 + i * 16 + ml) * 40 + kq);
    #pragma unroll
    for (int j = 0; j < 8; j++) bfr[j] = *(const bf16x8*)(Ts + (j * 16 + ml) * 40 + kq);
    #pragma unroll
    for (int i = 0; i < 2; i++)
      #pragma unroll
      for (int j = 0; j < 8; j++)
        acc[i][j] = __builtin_amdgcn_mfma_f32_16x16x32_bf16(afr[i], bfr[j], acc[i][j], 0, 0, 0);
  }
  #pragma unroll
  for (int i = 0; i < 2; i++)
    #pragma unroll
    for (int j = 0; j < 8; j++)
      #pragma unroll
      for (int r = 0; r < 4; r++) {
        int c = w * 32 + i * 16 + rq + r, d = j * 16 + ml;
        dotc[(size_t)bh * 16384 + c * 128 + d] = acc[i][j][r];
      }
}

// softmax over d: logits = tau[hc]/sqrt(N) * (2*dotc - diag[c] - diag[d])
__global__ __launch_bounds__(128) void chsm_kernel(const float* __restrict__ dotc,
                                                   const float* __restrict__ tau,
                                                   bf16* __restrict__ attnc) {
  int bh = blockIdx.x, hc = bh & 7;
  int c = threadIdx.x;
  const float* dp = dotc + (size_t)bh * 16384;
  __shared__ float diag[128];
  diag[c] = dp[c * 128 + c];
  __syncthreads();
  float sc = tau[hc] * rsqrtf(2048.f);
  float qc = diag[c];
  float mx = -1e30f;
  for (int d = 0; d < 128; d++) {
    float lg = sc * (2.f * dp[c * 128 + d] - qc - diag[d]);
    mx = fmaxf(mx, lg);
  }
  float sum = 0.f;
  for (int d = 0; d < 128; d++) {
    float lg = sc * (2.f * dp[c * 128 + d] - qc - diag[d]);
    sum += expf(lg - mx);
  }
  float inv = 1.f / sum;
  for (int d = 0; d < 128; d++) {
    float lg = sc * (2.f * dp[c * 128 + d] - qc - diag[d]);
    attnc[(size_t)bh * 16384 + c * 128 + d] = (bf16)(expf(lg - mx) * inv);
  }
}

// wc[c][n] = sum_d attnc[c][d] * vc[b][n][hc*128+d]; write wcn (B,N,D)
// grid (32 nchunks of 64, 16 bh)
__global__ __launch_bounds__(256) void chav_kernel(const bf16* __restrict__ attnc,
                                                   const bf16* __restrict__ vc,
                                                   bf16* __restrict__ wcn) {
  int nb = blockIdx.x, bh = blockIdx.y;
  int b = bh >> 3, hc = bh & 7;
  int n0 = nb * 64;
  __shared__ bf16 As[128 * 136];
  __shared__ bf16 Bs[64 * 136];
  int t = threadIdx.x, lane = t & 63, w = t >> 6;
  int ml = lane & 15, kq = (lane >> 4) * 8, rq = (lane >> 4) * 4;
  #pragma unroll
  for (int u = 0; u < 8; u++) {                  // A: 128 rows x 16 x 16B
    int idx = u * 256 + t;
    int r = idx >> 4, seg = (idx & 15) * 8;
    *(uint4*)(As + r * 136 + seg) = *(const uint4*)(attnc + (size_t)bh * 16384 + r * 128 + seg);
  }
  #pragma unroll
  for (int u = 0; u < 4; u++) {                  // B: 64 rows x 16 x 16B
    int idx = u * 256 + t;
    int r = idx >> 4, seg = (idx & 15) * 8;
    *(uint4*)(Bs + r * 136 + seg) =
        *(const uint4*)(vc + (size_t)(b * 2048 + n0 + r) * 1024 + hc * 128 + seg);
  }
  __syncthreads();
  f32x4 acc[2][4] = {};
  #pragma unroll
  for (int ks = 0; ks < 4; ks++) {
    bf16x8 afr[2], bfr[4];
    #pragma unroll
    for (int i = 0; i < 2; i++)
      afr[i] = *(const bf16x8*)(As + (w * 32 + i * 16 + ml) * 136 + ks * 32 + kq);
    #pragma unroll
    for (int j = 0; j < 4; j++)
      bfr[j] = *(const bf16x8*)(Bs + (j * 16 + ml) * 136 + ks * 32 + kq);
    #pragma unroll
    for (int i = 0; i < 2; i++)
      #pragma unroll
      for (int j = 0; j < 4; j++)
        acc[i][j] = __builtin_amdgcn_mfma_f32_16x16x32_bf16(afr[i], bfr[j], acc[i][j], 0, 0, 0);
  }
  #pragma unroll
  for (int i = 0; i < 2; i++)
    #pragma unroll
    for (int j = 0; j < 4; j++)
      #pragma unroll
      for (int r = 0; r < 4; r++) {
        int c = w * 32 + i * 16 + rq + r;
        int n = n0 + j * 16 + ml;
        wcn[(size_t)(b * 2048 + n) * 1024 + hc * 128 + c] = (bf16)acc[i][j][r];
      }
}

// ============================================================
// Host launcher
// ============================================================
extern "C" void kernel_launch(void* const* d_in, const int* in_sizes, int n_in,
                              void* d_out, int out_size, void* d_ws, size_t ws_size,
                              hipStream_t stream) {
  const float* x      = (const float*)d_in[0];
  const float* t      = (const float*)d_in[1];
  const float* n1s    = (const float*)d_in[2];
  const float* n1b    = (const float*)d_in[3];
  const float* n2s    = (const float*)d_in[4];
  const float* n2b    = (const float*)d_in[5];
  const float* tc_w1  = (const float*)d_in[6];
  const float* tc_b1  = (const float*)d_in[7];
  const float* tc_w2  = (const float*)d_in[8];
  const float* tc_b2  = (const float*)d_in[9];
  const float* tc_wa  = (const float*)d_in[10];
  const float* tc_ba  = (const float*)d_in[11];
  const float* tc_wc  = (const float*)d_in[12];
  const float* tc_bc  = (const float*)d_in[13];
  const float* aqk_w  = (const float*)d_in[14];
  const float* av_w   = (const float*)d_in[15];
  const float* aout_w = (const float*)d_in[16];
  const float* doobw  = (const float*)d_in[17];
  const float* doobb  = (const float*)d_in[18];
  const float* cqk_w  = (const float*)d_in[19];
  const float* cv_w   = (const float*)d_in[20];
  const float* cout_w = (const float*)d_in[21];
  const float* tau    = (const float*)d_in[22];
  const float* g1     = (const float*)d_in[23];
  const float* g2     = (const float*)d_in[24];
  float* out = (float*)d_out;

  // workspace arena
  char* p = (char*)d_ws;
  auto alloc = [&](size_t bytes) -> void* {
    void* r = (void*)p;
    p += (bytes + 255) & ~(size_t)255;
    return r;
  };
  float* emb   = (float*)alloc(2 * 4096 * 4);
  float* partA = (float*)alloc(32 * 2 * 4096 * 4);
  float* partB = (float*)alloc(32 * 2 * 4096 * 4);
  float* h1    = (float*)alloc(2 * 4096 * 4);
  float* h2    = (float*)alloc(2 * 4096 * 4);
  float* avec  = (float*)alloc(2 * 4096 * 4);
  float* cvec  = (float*)alloc(2 * 4096 * 4);
  float* sca   = (float*)alloc(2 * 1024 * 4);
  float* scc   = (float*)alloc(2 * 1024 * 4);
  float* agv   = (float*)alloc(2 * 1024 * 4);
  float* cgv   = (float*)alloc(2 * 1024 * 4);
  float* q2buf = (float*)alloc(2 * 16 * 2048 * 4);
  float* ebuf  = (float*)alloc(2 * 16 * 2048 * 4);
  float* dotc  = (float*)alloc(16 * 128 * 128 * 4);
  bf16* attnc  = (bf16*)alloc(16 * 128 * 128 * 2);
  bf16* wt     = (bf16*)alloc((size_t)6 * 1024 * 1024 * 2);
  bf16* xbf    = (bf16*)alloc((size_t)M_ * 1024 * 2);
  bf16* qkbf   = (bf16*)alloc((size_t)M_ * 1024 * 2);
  bf16* vbuf   = (bf16*)alloc((size_t)M_ * 1024 * 2);
  bf16* wbuf   = (bf16*)alloc((size_t)M_ * 1024 * 2);
  (void)ws_size; (void)in_sizes; (void)n_in; (void)out_size;

  bf16* wt_qk   = wt + (size_t)0 * 1048576;
  bf16* wt_v    = wt + (size_t)1 * 1048576;
  bf16* wt_out  = wt + (size_t)2 * 1048576;
  bf16* wt_cqk  = wt + (size_t)3 * 1048576;
  bf16* wt_cv   = wt + (size_t)4 * 1048576;
  bf16* wt_cout = wt + (size_t)5 * 1048576;

  dim3 blk(256);
  // --- weight convert+transpose (independent) ---
  wtconv_kernel<<<dim3(32, 32), blk, 0, stream>>>(aqk_w,  wt_qk);
  wtconv_kernel<<<dim3(32, 32), blk, 0, stream>>>(av_w,   wt_v);
  wtconv_kernel<<<dim3(32, 32), blk, 0, stream>>>(aout_w, wt_out);
  wtconv_kernel<<<dim3(32, 32), blk, 0, stream>>>(cqk_w,  wt_cqk);
  wtconv_kernel<<<dim3(32, 32), blk, 0, stream>>>(cv_w,   wt_cv);
  wtconv_kernel<<<dim3(32, 32), blk, 0, stream>>>(cout_w, wt_cout);

  // --- stage A: time conditioning ---
  emb_kernel<<<32, blk, 0, stream>>>(t, emb);
  gemv_kernel<<<dim3(8, 32), blk, 0, stream>>>(emb, tc_w1, partA);
  gemv_reduce_kernel<<<32, blk, 0, stream>>>(partA, tc_b1, h1, 1);
  gemv_kernel<<<dim3(8, 32), blk, 0, stream>>>(h1, tc_w2, partA);
  gemv_reduce_kernel<<<32, blk, 0, stream>>>(partA, tc_b2, h2, 1);
  gemv_kernel<<<dim3(8, 32), blk, 0, stream>>>(h2, tc_wa, partA);
  gemv_kernel<<<dim3(8, 32), blk, 0, stream>>>(h2, tc_wc, partB);
  gemv_reduce_kernel<<<32, blk, 0, stream>>>(partA, tc_ba, avec, 0);
  gemv_reduce_kernel<<<32, blk, 0, stream>>>(partB, tc_bc, cvec, 0);
  postA_kernel<<<8, blk, 0, stream>>>(avec, cvec, g1, g2, sca, scc, agv, cgv);

  // --- token attention ---
  ln_mod_kernel<<<4096, blk, 0, stream>>>(x, n1s, n1b, avec, xbf);
  gemm_kernel<1><<<dim3(32, 8), blk, 0, stream>>>(xbf, wt_qk, sca, nullptr, qkbf);
  gemm_kernel<3><<<dim3(32, 8), blk, 0, stream>>>(xbf, wt_v, nullptr, nullptr, vbuf);
  phiq2_kernel<<<4096, blk, 0, stream>>>(xbf, qkbf, doobw, doobb, q2buf, ebuf);
  flash_kernel<<<dim3(16, 32), blk, 0, stream>>>(qkbf, vbuf, q2buf, ebuf, wbuf);
  gemm_kernel<4><<<dim3(32, 8), blk, 0, stream>>>(wbuf, wt_out, agv, x, out);

  // --- channel attention ---
  ln_mod_kernel<<<4096, blk, 0, stream>>>(out, n2s, n2b, cvec, xbf);
  gemm_kernel<2><<<dim3(32, 8), blk, 0, stream>>>(xbf, wt_cqk, scc, nullptr, qkbf);
  gemm_kernel<0><<<dim3(32, 8), blk, 0, stream>>>(xbf, wt_cv, nullptr, nullptr, vbuf);
  gram_kernel<<<16, blk, 0, stream>>>(qkbf, dotc);
  chsm_kernel<<<16, dim3(128), 0, stream>>>(dotc, tau, attnc);
  chav_kernel<<<dim3(32, 16), blk, 0, stream>>>(attnc, vbuf, wbuf);
  gemm_kernel<4><<<dim3(32, 8), blk, 0, stream>>>(wbuf, wt_cout, cgv, out, out);
}

// Round 2
// 594.777 us; speedup vs baseline: 1.3233x; 1.3233x over previous
//
#include <hip/hip_runtime.h>
#include <hip/hip_bf16.h>
#include <math.h>

typedef __bf16 bf16;
typedef bf16 bf16x8 __attribute__((ext_vector_type(8)));
typedef float f32x4 __attribute__((ext_vector_type(4)));

#define B_   2
#define N_   2048
#define D_   1024
#define H_   16
#define HC_  8
#define M_   (B_*N_)   // 4096 rows in all big GEMMs

// async global->LDS 16B: lds dest = wave-uniform base + lane*16
__device__ __forceinline__ void gl16(const bf16* g, bf16* lds_base) {
#if __has_builtin(__builtin_amdgcn_global_load_lds)
  __builtin_amdgcn_global_load_lds((const __attribute__((address_space(1))) void*)g,
                                   (__attribute__((address_space(3))) void*)lds_base,
                                   16, 0, 0);
#else
  int lane = threadIdx.x & 63;
  *(uint4*)(lds_base + lane * 8) = *(const uint4*)g;
#endif
}

// ============================================================
// Stage A: time-conditioning MLP (GEMV, B=2 rows)
// ============================================================
__global__ __launch_bounds__(256) void emb_kernel(const float* __restrict__ tin,
                                                  float* __restrict__ emb) {
  int idx = blockIdx.x * 256 + threadIdx.x;   // 0..8191
  int b = idx >> 12, p = idx & 4095;
  float tv = tin[b];
  int half = p & 2047;
  float freq = expf(-logf(10000.f) * (float)half * (1.f / 2048.f));
  float arg = tv * freq;
  emb[idx] = (p < 2048) ? cosf(arg) : sinf(arg);
}

__global__ __launch_bounds__(256) void gemv_kernel(const float* __restrict__ x,
                                                   const float* __restrict__ W,
                                                   float* __restrict__ part) {
  __shared__ float xs[2][128];
  int t = threadIdx.x;
  int j0 = blockIdx.x * 512;
  int k0 = blockIdx.y * 128;
  if (t < 128) xs[0][t] = x[k0 + t];
  else         xs[1][t - 128] = x[4096 + k0 + (t - 128)];
  __syncthreads();
  float a00 = 0.f, a01 = 0.f, a10 = 0.f, a11 = 0.f;
  int j = j0 + t * 2;
  #pragma unroll 8
  for (int k = 0; k < 128; k++) {
    float2 wv = *(const float2*)(W + (size_t)(k0 + k) * 4096 + j);
    float x0 = xs[0][k], x1 = xs[1][k];
    a00 += x0 * wv.x; a01 += x0 * wv.y;
    a10 += x1 * wv.x; a11 += x1 * wv.y;
  }
  *(float2*)(part + (size_t)(blockIdx.y * 2 + 0) * 4096 + j) = make_float2(a00, a01);
  *(float2*)(part + (size_t)(blockIdx.y * 2 + 1) * 4096 + j) = make_float2(a10, a11);
}

__global__ __launch_bounds__(256) void gemv_reduce_kernel(const float* __restrict__ part,
                                                          const float* __restrict__ bias,
                                                          float* __restrict__ y, int act) {
  int idx = blockIdx.x * 256 + threadIdx.x;   // 0..8191
  int b = idx >> 12, j = idx & 4095;
  float s = bias[j];
  #pragma unroll
  for (int kc = 0; kc < 32; kc++) s += part[(size_t)(kc * 2 + b) * 4096 + j];
  if (act) s = s / (1.f + expf(-s));          // silu
  y[idx] = s;
}

__global__ __launch_bounds__(256) void postA_kernel(const float* __restrict__ avec,
                                                    const float* __restrict__ cvec,
                                                    const float* __restrict__ g1,
                                                    const float* __restrict__ g2,
                                                    float* __restrict__ sca, float* __restrict__ scc,
                                                    float* __restrict__ agv, float* __restrict__ cgv) {
  int idx = blockIdx.x * 256 + threadIdx.x;   // 0..2047
  int b = idx >> 10, d = idx & 1023;
  sca[idx] = expf(avec[b * 4096 + 3072 + d]);
  scc[idx] = expf(cvec[b * 4096 + 3072 + d]);
  agv[idx] = avec[b * 4096 + 2048 + d] * g1[d];
  cgv[idx] = cvec[b * 4096 + 2048 + d] * g2[d];
}

// ============================================================
// Weight fp32 (K x N) -> bf16 transposed (N x K), 6 weights in one launch
// ============================================================
__global__ __launch_bounds__(256) void wtconv6_kernel(const float* w0, const float* w1,
                                                      const float* w2, const float* w3,
                                                      const float* w4, const float* w5,
                                                      bf16* o0, bf16* o1, bf16* o2,
                                                      bf16* o3, bf16* o4, bf16* o5) {
  const float* W; bf16* Wt;
  switch (blockIdx.z) {
    case 0: W = w0; Wt = o0; break;
    case 1: W = w1; Wt = o1; break;
    case 2: W = w2; Wt = o2; break;
    case 3: W = w3; Wt = o3; break;
    case 4: W = w4; Wt = o4; break;
    default: W = w5; Wt = o5; break;
  }
  __shared__ float tile[32][33];
  int t = threadIdx.x;
  int i = t >> 5, j = t & 31;
  int n0 = blockIdx.x * 32, k0 = blockIdx.y * 32;
  #pragma unroll
  for (int u = 0; u < 4; u++) {
    int k = i + u * 8;
    tile[k][j] = W[(size_t)(k0 + k) * 1024 + n0 + j];
  }
  __syncthreads();
  #pragma unroll
  for (int u = 0; u < 4; u++) {
    int n = i + u * 8;
    Wt[(size_t)(n0 + n) * 1024 + k0 + j] = (bf16)tile[j][n];
  }
}

// ============================================================
// LayerNorm + modulate -> bf16 (+ optional phi = x1 . doob_w)
// ============================================================
__global__ __launch_bounds__(256) void ln_mod_kernel(const float* __restrict__ xin,
                                                     const float* __restrict__ nsc,
                                                     const float* __restrict__ nbi,
                                                     const float* __restrict__ mod,
                                                     const float* __restrict__ doobw,
                                                     float* __restrict__ phi,
                                                     bf16* __restrict__ outp) {
  int row = blockIdx.x;              // 0..4095
  int b = row >> 11;
  int t = threadIdx.x;
  const float* xr = xin + (size_t)row * 1024;
  float v[4], s = 0.f, ss = 0.f;
  #pragma unroll
  for (int u = 0; u < 4; u++) { v[u] = xr[t + u * 256]; s += v[u]; ss += v[u] * v[u]; }
  #pragma unroll
  for (int off = 1; off < 64; off <<= 1) { s += __shfl_xor(s, off, 64); ss += __shfl_xor(ss, off, 64); }
  __shared__ float sb[4], ssb[4], pb[4];
  if ((t & 63) == 0) { sb[t >> 6] = s; ssb[t >> 6] = ss; }
  __syncthreads();
  s = sb[0] + sb[1] + sb[2] + sb[3];
  ss = ssb[0] + ssb[1] + ssb[2] + ssb[3];
  float mu = s * (1.f / 1024.f);
  float var = ss * (1.f / 1024.f) - mu * mu;
  float rs = rsqrtf(var + 1e-6f);
  const float* shv = mod + b * 4096;
  const float* scv = mod + b * 4096 + 1024;
  float ph = 0.f;
  #pragma unroll
  for (int u = 0; u < 4; u++) {
    int d = t + u * 256;
    float y = (v[u] - mu) * rs * nsc[d] + nbi[d];
    float ym = y * (1.f + scv[d]) + shv[d];
    outp[(size_t)row * 1024 + d] = (bf16)ym;
    if (doobw) ph += ym * doobw[d];
  }
  if (doobw) {
    #pragma unroll
    for (int off = 1; off < 64; off <<= 1) ph += __shfl_xor(ph, off, 64);
    if ((t & 63) == 0) pb[t >> 6] = ph;
    __syncthreads();
    if (t == 0) phi[row] = pb[0] + pb[1] + pb[2] + pb[3];
  }
}

__global__ __launch_bounds__(256) void phimax_kernel(const float* __restrict__ phi,
                                                     float* __restrict__ pm) {
  int b = blockIdx.x;
  int t = threadIdx.x;
  float m = -1e30f;
  #pragma unroll
  for (int u = 0; u < 8; u++) m = fmaxf(m, phi[b * 2048 + t + u * 256]);
  #pragma unroll
  for (int off = 1; off < 64; off <<= 1) m = fmaxf(m, __shfl_xor(m, off, 64));
  __shared__ float mb[4];
  if ((t & 63) == 0) mb[t >> 6] = m;
  __syncthreads();
  if (t == 0) pm[b] = fmaxf(fmaxf(mb[0], mb[1]), fmaxf(mb[2], mb[3]));
}

// ============================================================
// bf16 MFMA GEMM w/ global_load_lds staging, XOR-swizzled LDS (stride 64, no pad)
// TM in {64,128}, N-tile = 128. 2x2 waves.
// MODE 10: token fused out: col<1024 -> qk = val*sca (B,N,D); col>=1024 -> vt (B,H,64,N)
// MODE 11: channel fused:   col<1024 -> qkct = val*scc (B,HC,128,N); col>=1024 -> v (B,N,D)
// MODE 4 : out = resid + val*gate (fp32, B,N,D)
// ============================================================
template <int MODE, int TM>
__global__ __launch_bounds__(256) void gemm_kernel(const bf16* __restrict__ A,
                                                   const bf16* __restrict__ Wt,
                                                   const float* __restrict__ scale,
                                                   const float* __restrict__ resid,
                                                   void* __restrict__ out0,
                                                   void* __restrict__ out1) {
  constexpr int K = 1024;
  constexpr int WM = TM / 2;       // wave rows
  constexpr int IT = WM / 16;      // i tiles per wave
  __shared__ bf16 As[TM * 64];
  __shared__ bf16 Bs[128 * 64];
  const int m0 = blockIdx.x * TM;
  const int n0 = blockIdx.y * 128;
  const int t = threadIdx.x, lane = t & 63, wid = t >> 6;
  const int wy = wid >> 1, wx = wid & 1;
  const int ml = lane & 15, quad = lane >> 4, rq = quad * 4, kq = quad * 8;
  // staging: lane -> (row srow, swizzled source chunk)
  const int srow = lane >> 3;
  const int schunk = (lane & 7) ^ srow;
  const bf16* gA = A  + (size_t)(m0 + wid * (TM / 4) + srow) * K + schunk * 8;
  const bf16* gB = Wt + (size_t)(n0 + wid * 32 + srow) * K + schunk * 8;
  bf16* lA = As + (wid * (TM / 4)) * 64;
  bf16* lB = Bs + (wid * 32) * 64;
  const int mlm = ml & 7;

  f32x4 acc[IT][4] = {};
  for (int k0 = 0; k0 < K; k0 += 64) {
    __syncthreads();
    #pragma unroll
    for (int q = 0; q < TM / 32; q++)
      gl16(gA + (size_t)q * 8 * K + k0, lA + q * 8 * 64);
    #pragma unroll
    for (int q = 0; q < 4; q++)
      gl16(gB + (size_t)q * 8 * K + k0, lB + q * 8 * 64);
    __syncthreads();
    #pragma unroll
    for (int ks = 0; ks < 2; ks++) {
      const int slot = ((ks * 4 + quad) ^ mlm) * 8;
      bf16x8 af[IT], bfv[4];
      #pragma unroll
      for (int i = 0; i < IT; i++)
        af[i] = *(const bf16x8*)(As + (wy * WM + i * 16 + ml) * 64 + slot);
      #pragma unroll
      for (int j = 0; j < 4; j++)
        bfv[j] = *(const bf16x8*)(Bs + (wx * 64 + j * 16 + ml) * 64 + slot);
      #pragma unroll
      for (int i = 0; i < IT; i++)
        #pragma unroll
        for (int j = 0; j < 4; j++)
          acc[i][j] = __builtin_amdgcn_mfma_f32_16x16x32_bf16(af[i], bfv[j], acc[i][j], 0, 0, 0);
    }
  }
  // epilogue
  #pragma unroll
  for (int i = 0; i < IT; i++) {
    #pragma unroll
    for (int j = 0; j < 4; j++) {
      int col = n0 + wx * 64 + j * 16 + ml;
      #pragma unroll
      for (int r = 0; r < 4; r++) {
        int row = m0 + wy * WM + i * 16 + rq + r;
        int b = row >> 11, n = row & 2047;
        float val = acc[i][j][r];
        if constexpr (MODE == 10) {
          if (col < 1024) {
            ((bf16*)out0)[(size_t)row * 1024 + col] = (bf16)(val * scale[b * 1024 + col]);
          } else {
            int c2 = col - 1024;
            ((bf16*)out1)[((size_t)((b * 16 + (c2 >> 6)) * 64 + (c2 & 63))) * 2048 + n] = (bf16)val;
          }
        } else if constexpr (MODE == 11) {
          if (col < 1024) {
            float sv = val * scale[b * 1024 + col];
            ((bf16*)out0)[((size_t)((b * 8 + (col >> 7)) * 128 + (col & 127))) * 2048 + n] = (bf16)sv;
          } else {
            ((bf16*)out1)[(size_t)row * 1024 + (col - 1024)] = (bf16)val;
          }
        } else {
          float g = scale[b * 1024 + col];
          ((float*)out0)[(size_t)row * 1024 + col] =
              resid[(size_t)row * 1024 + col] + val * g;
        }
      }
    }
  }
}

// ============================================================
// q2 per (b,h,n) + e = phi - q2 - phimax[b]
// ============================================================
__global__ __launch_bounds__(256) void q2e_kernel(const bf16* __restrict__ qk,
                                                  const float* __restrict__ phi,
                                                  const float* __restrict__ pm,
                                                  float* __restrict__ q2buf,
                                                  float* __restrict__ ebuf) {
  int row = blockIdx.x;              // b*2048+n
  int b = row >> 11, n = row & 2047;
  int t = threadIdx.x;
  const bf16* qr = qk + (size_t)row * 1024;
  __shared__ float q2s[16][17];
  {
    int h = t >> 4, i0 = (t & 15) * 4;
    float q = 0.f;
    #pragma unroll
    for (int u = 0; u < 4; u++) { float qv = (float)qr[h * 64 + i0 + u]; q += qv * qv; }
    q2s[h][t & 15] = q;
  }
  __syncthreads();
  if (t < 16) {
    float q2 = 0.f;
    #pragma unroll
    for (int u = 0; u < 16; u++) q2 += q2s[t][u];
    q2buf[(size_t)(b * 16 + t) * 2048 + n] = q2;
    ebuf [(size_t)(b * 16 + t) * 2048 + n] = phi[row] - q2 - pm[b];
  }
}

// ============================================================
// Flash attention, static-max softmax (no online rescale).
// grid (32 mtiles, 32 bh); 256 thr = 4 waves; 64 Q-rows/block, wave owns 16 rows.
// ============================================================
__global__ __launch_bounds__(256) void flash_kernel(const bf16* __restrict__ qk,  // (B,N,D)
                                                    const bf16* __restrict__ vt,  // (B,H,64,N)
                                                    const float* __restrict__ q2buf,
                                                    const float* __restrict__ ebuf,
                                                    bf16* __restrict__ wout) {    // (B,N,D)
  int mt = blockIdx.x, bh = blockIdx.y;
  int b = bh >> 4, h = bh & 15;
  int m0 = mt * 64;
  int t = threadIdx.x, lane = t & 63, w = t >> 6;
  int ml = lane & 15, kq = (lane >> 4) * 8, rq = (lane >> 4) * 4;

  __shared__ bf16 Qs[64 * 72];
  __shared__ bf16 Ks[64 * 72];
  __shared__ bf16 Vs[64 * 72];   // Vs[dh][n]
  __shared__ bf16 Ps[64 * 72];

  #pragma unroll
  for (int u = 0; u < 2; u++) {                      // Q: 64 rows x 8 x 16B
    int idx = u * 256 + t;
    int r = idx >> 3, seg = (idx & 7) * 8;
    *(uint4*)(Qs + r * 72 + seg) =
        *(const uint4*)(qk + (size_t)(b * 2048 + m0 + r) * 1024 + h * 64 + seg);
  }
  float q2l[4], rsum[4];
  const float* q2p = q2buf + (size_t)bh * 2048 + m0;
  #pragma unroll
  for (int r = 0; r < 4; r++) {
    q2l[r] = q2p[w * 16 + rq + r] * 1.44269504f;
    rsum[r] = 0.f;
  }
  f32x4 oacc[4] = {};
  const float* ep = ebuf + (size_t)bh * 2048;

  for (int nc = 0; nc < 32; nc++) {
    int n0c = nc * 64;
    __syncthreads();
    #pragma unroll
    for (int u = 0; u < 2; u++) {                    // K,V chunk: 64 rows x 8 x 16B
      int idx = u * 256 + t;
      int r = idx >> 3, seg = (idx & 7) * 8;
      *(uint4*)(Ks + r * 72 + seg) =
          *(const uint4*)(qk + (size_t)(b * 2048 + n0c + r) * 1024 + h * 64 + seg);
      *(uint4*)(Vs + r * 72 + seg) =
          *(const uint4*)(vt + (size_t)(bh * 64 + r) * 2048 + n0c + seg);
    }
    __syncthreads();

    f32x4 sacc[4] = {};
    #pragma unroll
    for (int ks = 0; ks < 2; ks++) {
      bf16x8 qa = *(const bf16x8*)(Qs + (w * 16 + ml) * 72 + ks * 32 + kq);
      #pragma unroll
      for (int j = 0; j < 4; j++) {
        bf16x8 kb = *(const bf16x8*)(Ks + (j * 16 + ml) * 72 + ks * 32 + kq);
        sacc[j] = __builtin_amdgcn_mfma_f32_16x16x32_bf16(qa, kb, sacc[j], 0, 0, 0);
      }
    }

    float ejs[4];
    #pragma unroll
    for (int j = 0; j < 4; j++) ejs[j] = ep[n0c + j * 16 + ml] * 1.44269504f;
    #pragma unroll
    for (int r = 0; r < 4; r++) {
      int prow = (w * 16 + rq + r) * 72;
      float ps = 0.f;
      #pragma unroll
      for (int j = 0; j < 4; j++) {
        float p = exp2f(fmaf(2.88539008f, sacc[j][r], ejs[j] - q2l[r]));
        Ps[prow + j * 16 + ml] = (bf16)p;
        ps += p;
      }
      rsum[r] += ps;
    }
    // Ps strip is wave-private: no barrier needed (in-wave LDS ordering)
    #pragma unroll
    for (int ks = 0; ks < 2; ks++) {
      bf16x8 pa = *(const bf16x8*)(Ps + (w * 16 + ml) * 72 + ks * 32 + kq);
      #pragma unroll
      for (int jd = 0; jd < 4; jd++) {
        bf16x8 vb = *(const bf16x8*)(Vs + (jd * 16 + ml) * 72 + ks * 32 + kq);
        oacc[jd] = __builtin_amdgcn_mfma_f32_16x16x32_bf16(pa, vb, oacc[jd], 0, 0, 0);
      }
    }
  }
  #pragma unroll
  for (int r = 0; r < 4; r++) {
    rsum[r] += __shfl_xor(rsum[r], 1, 64);
    rsum[r] += __shfl_xor(rsum[r], 2, 64);
    rsum[r] += __shfl_xor(rsum[r], 4, 64);
    rsum[r] += __shfl_xor(rsum[r], 8, 64);
    rsum[r] = 1.f / rsum[r];
  }
  #pragma unroll
  for (int jd = 0; jd < 4; jd++)
    #pragma unroll
    for (int r = 0; r < 4; r++) {
      int row = w * 16 + rq + r;
      wout[(size_t)(b * 2048 + m0 + row) * 1024 + h * 64 + jd * 16 + ml] =
          (bf16)(oacc[jd][r] * rsum[r]);
    }
}

// ============================================================
// Channel attention
// ============================================================
// split-K Gram: grid (16 bh, 8 kslice): dotp[(ks*16+bh)][c][d] over 256-deep slice
__global__ __launch_bounds__(256) void gram_kernel(const bf16* __restrict__ qkct,
                                                   float* __restrict__ dotp) {
  int bh = blockIdx.x, ksl = blockIdx.y;
  const bf16* Q = qkct + (size_t)bh * 128 * 2048 + ksl * 256;
  __shared__ bf16 Ts[128 * 40];
  int t = threadIdx.x, lane = t & 63, w = t >> 6;
  int ml = lane & 15, kq = (lane >> 4) * 8, rq = (lane >> 4) * 4;
  f32x4 acc[2][8] = {};
  for (int k0 = 0; k0 < 256; k0 += 32) {
    __syncthreads();
    #pragma unroll
    for (int u = 0; u < 2; u++) {
      int idx = u * 256 + t;                 // 512 units: 128 rows x 4 x 16B
      int r = idx >> 2, seg = (idx & 3) * 8;
      *(uint4*)(Ts + r * 40 + seg) = *(const uint4*)(Q + (size_t)r * 2048 + k0 + seg);
    }
    __syncthreads();
    bf16x8 afr[2], bfr[8];
    #pragma unroll
    for (int i = 0; i < 2; i++) afr[i] = *(const bf16x8*)(Ts + (w * 32 + i * 16 + ml) * 40 + kq);
    #pragma unroll
    for (int j = 0; j < 8; j++) bfr[j] = *(const bf16x8*)(Ts + (j * 16 + ml) * 40 + kq);
    #pragma unroll
    for (int i = 0; i < 2; i++)
      #pragma unroll
      for (int j = 0; j < 8; j++)
        acc[i][j] = __builtin_amdgcn_mfma_f32_16x16x32_bf16(afr[i], bfr[j], acc[i][j], 0, 0, 0);
  }
  float* outp = dotp + ((size_t)ksl * 16 + bh) * 16384;
  #pragma unroll
  for (int i = 0; i < 2; i++)
    #pragma unroll
    for (int j = 0; j < 8; j++)
      #pragma unroll
      for (int r = 0; r < 4; r++) {
        int c = w * 32 + i * 16 + rq + r, d = j * 16 + ml;
        outp[c * 128 + d] = acc[i][j][r];
      }
}

// softmax over d, folding the 8-way partial sum. grid 2048 (bh*128+c), 128 thr.
__global__ __launch_bounds__(128) void chsm_kernel(const float* __restrict__ dotp,
                                                   const float* __restrict__ tau,
                                                   bf16* __restrict__ attnc) {
  int blk = blockIdx.x;
  int bh = blk >> 7, c = blk & 127, hc = bh & 7;
  int d = threadIdx.x;
  float dot = 0.f, dd = 0.f;
  #pragma unroll
  for (int kc = 0; kc < 8; kc++) {
    const float* pp = dotp + ((size_t)kc * 16 + bh) * 16384;
    dot += pp[c * 128 + d];
    dd  += pp[d * 128 + d];
  }
  __shared__ float diag[128];
  __shared__ float red[2], red2[2];
  diag[d] = dd;
  __syncthreads();
  float qc = diag[c];
  float sc = tau[hc] * rsqrtf(2048.f);
  float lg = sc * (2.f * dot - qc - dd);
  float mx = lg;
  #pragma unroll
  for (int off = 1; off < 64; off <<= 1) mx = fmaxf(mx, __shfl_xor(mx, off, 64));
  if ((d & 63) == 0) red[d >> 6] = mx;
  __syncthreads();
  mx = fmaxf(red[0], red[1]);
  float e = exp2f((lg - mx) * 1.44269504f);
  float sm = e;
  #pragma unroll
  for (int off = 1; off < 64; off <<= 1) sm += __shfl_xor(sm, off, 64);
  if ((d & 63) == 0) red2[d >> 6] = sm;
  __syncthreads();
  sm = red2[0] + red2[1];
  attnc[(size_t)bh * 16384 + c * 128 + d] = (bf16)(e / sm);
}

// wc[c][n] = sum_d attnc[c][d] * vc[b][n][hc*128+d]; write wcn (B,N,D)
__global__ __launch_bounds__(256) void chav_kernel(const bf16* __restrict__ attnc,
                                                   const bf16* __restrict__ vc,
                                                   bf16* __restrict__ wcn) {
  int nb = blockIdx.x, bh = blockIdx.y;
  int b = bh >> 3, hc = bh & 7;
  int n0 = nb * 64;
  __shared__ bf16 As[128 * 136];
  __shared__ bf16 Bs[64 * 136];
  int t = threadIdx.x, lane = t & 63, w = t >> 6;
  int ml = lane & 15, kq = (lane >> 4) * 8, rq = (lane >> 4) * 4;
  #pragma unroll
  for (int u = 0; u < 8; u++) {                  // A: 128 rows x 16 x 16B
    int idx = u * 256 + t;
    int r = idx >> 4, seg = (idx & 15) * 8;
    *(uint4*)(As + r * 136 + seg) = *(const uint4*)(attnc + (size_t)bh * 16384 + r * 128 + seg);
  }
  #pragma unroll
  for (int u = 0; u < 4; u++) {                  // B: 64 rows x 16 x 16B
    int idx = u * 256 + t;
    int r = idx >> 4, seg = (idx & 15) * 8;
    *(uint4*)(Bs + r * 136 + seg) =
        *(const uint4*)(vc + (size_t)(b * 2048 + n0 + r) * 1024 + hc * 128 + seg);
  }
  __syncthreads();
  f32x4 acc[2][4] = {};
  #pragma unroll
  for (int ks = 0; ks < 4; ks++) {
    bf16x8 afr[2], bfr[4];
    #pragma unroll
    for (int i = 0; i < 2; i++)
      afr[i] = *(const bf16x8*)(As + (w * 32 + i * 16 + ml) * 136 + ks * 32 + kq);
    #pragma unroll
    for (int j = 0; j < 4; j++)
      bfr[j] = *(const bf16x8*)(Bs + (j * 16 + ml) * 136 + ks * 32 + kq);
    #pragma unroll
    for (int i = 0; i < 2; i++)
      #pragma unroll
      for (int j = 0; j < 4; j++)
        acc[i][j] = __builtin_amdgcn_mfma_f32_16x16x32_bf16(afr[i], bfr[j], acc[i][j], 0, 0, 0);
  }
  #pragma unroll
  for (int i = 0; i < 2; i++)
    #pragma unroll
    for (int j = 0; j < 4; j++)
      #pragma unroll
      for (int r = 0; r < 4; r++) {
        int c = w * 32 + i * 16 + rq + r;
        int n = n0 + j * 16 + ml;
        wcn[(size_t)(b * 2048 + n) * 1024 + hc * 128 + c] = (bf16)acc[i][j][r];
      }
}

// ============================================================
// Host launcher
// ============================================================
extern "C" void kernel_launch(void* const* d_in, const int* in_sizes, int n_in,
                              void* d_out, int out_size, void* d_ws, size_t ws_size,
                              hipStream_t stream) {
  const float* x      = (const float*)d_in[0];
  const float* t      = (const float*)d_in[1];
  const float* n1s    = (const float*)d_in[2];
  const float* n1b    = (const float*)d_in[3];
  const float* n2s    = (const float*)d_in[4];
  const float* n2b    = (const float*)d_in[5];
  const float* tc_w1  = (const float*)d_in[6];
  const float* tc_b1  = (const float*)d_in[7];
  const float* tc_w2  = (const float*)d_in[8];
  const float* tc_b2  = (const float*)d_in[9];
  const float* tc_wa  = (const float*)d_in[10];
  const float* tc_ba  = (const float*)d_in[11];
  const float* tc_wc  = (const float*)d_in[12];
  const float* tc_bc  = (const float*)d_in[13];
  const float* aqk_w  = (const float*)d_in[14];
  const float* av_w   = (const float*)d_in[15];
  const float* aout_w = (const float*)d_in[16];
  const float* doobw  = (const float*)d_in[17];
  const float* cqk_w  = (const float*)d_in[19];
  const float* cv_w   = (const float*)d_in[20];
  const float* cout_w = (const float*)d_in[21];
  const float* tau    = (const float*)d_in[22];
  const float* g1     = (const float*)d_in[23];
  const float* g2     = (const float*)d_in[24];
  float* out = (float*)d_out;

  char* p = (char*)d_ws;
  auto alloc = [&](size_t bytes) -> void* {
    void* r = (void*)p;
    p += (bytes + 255) & ~(size_t)255;
    return r;
  };
  float* emb   = (float*)alloc(2 * 4096 * 4);
  float* partA = (float*)alloc(32 * 2 * 4096 * 4);
  float* partB = (float*)alloc(32 * 2 * 4096 * 4);
  float* h1    = (float*)alloc(2 * 4096 * 4);
  float* h2    = (float*)alloc(2 * 4096 * 4);
  float* avec  = (float*)alloc(2 * 4096 * 4);
  float* cvec  = (float*)alloc(2 * 4096 * 4);
  float* sca   = (float*)alloc(2 * 1024 * 4);
  float* scc   = (float*)alloc(2 * 1024 * 4);
  float* agv   = (float*)alloc(2 * 1024 * 4);
  float* cgv   = (float*)alloc(2 * 1024 * 4);
  float* phi   = (float*)alloc(4096 * 4);
  float* pmax  = (float*)alloc(2 * 4);
  float* q2buf = (float*)alloc(2 * 16 * 2048 * 4);
  float* ebuf  = (float*)alloc(2 * 16 * 2048 * 4);
  float* dotp  = (float*)alloc((size_t)8 * 16 * 16384 * 4);
  bf16* attnc  = (bf16*)alloc(16 * 128 * 128 * 2);
  bf16* wt     = (bf16*)alloc((size_t)6 * 1024 * 1024 * 2);
  bf16* xbf    = (bf16*)alloc((size_t)M_ * 1024 * 2);
  bf16* qkbf   = (bf16*)alloc((size_t)M_ * 1024 * 2);
  bf16* vbuf   = (bf16*)alloc((size_t)M_ * 1024 * 2);
  bf16* wbuf   = (bf16*)alloc((size_t)M_ * 1024 * 2);
  (void)ws_size; (void)in_sizes; (void)n_in; (void)out_size;

  // concatenated (N x K) weights: token [qk; v] (2048x1024), channel [cqk; cv]
  bf16* wt_tok  = wt;                              // 2048 x 1024
  bf16* wt_out  = wt + (size_t)2 * 1048576;        // 1024 x 1024
  bf16* wt_ch   = wt + (size_t)3 * 1048576;        // 2048 x 1024
  bf16* wt_cout = wt + (size_t)5 * 1048576;        // 1024 x 1024

  dim3 blk(256);
  wtconv6_kernel<<<dim3(32, 32, 6), blk, 0, stream>>>(
      aqk_w, av_w, aout_w, cqk_w, cv_w, cout_w,
      wt_tok, wt_tok + (size_t)1048576, wt_out,
      wt_ch,  wt_ch  + (size_t)1048576, wt_cout);

  // --- stage A: time conditioning ---
  emb_kernel<<<32, blk, 0, stream>>>(t, emb);
  gemv_kernel<<<dim3(8, 32), blk, 0, stream>>>(emb, tc_w1, partA);
  gemv_reduce_kernel<<<32, blk, 0, stream>>>(partA, tc_b1, h1, 1);
  gemv_kernel<<<dim3(8, 32), blk, 0, stream>>>(h1, tc_w2, partA);
  gemv_reduce_kernel<<<32, blk, 0, stream>>>(partA, tc_b2, h2, 1);
  gemv_kernel<<<dim3(8, 32), blk, 0, stream>>>(h2, tc_wa, partA);
  gemv_kernel<<<dim3(8, 32), blk, 0, stream>>>(h2, tc_wc, partB);
  gemv_reduce_kernel<<<32, blk, 0, stream>>>(partA, tc_ba, avec, 0);
  gemv_reduce_kernel<<<32, blk, 0, stream>>>(partB, tc_bc, cvec, 0);
  postA_kernel<<<8, blk, 0, stream>>>(avec, cvec, g1, g2, sca, scc, agv, cgv);

  // --- token attention ---
  ln_mod_kernel<<<4096, blk, 0, stream>>>(x, n1s, n1b, avec, doobw, phi, xbf);
  phimax_kernel<<<2, blk, 0, stream>>>(phi, pmax);
  gemm_kernel<10, 128><<<dim3(32, 16), blk, 0, stream>>>(xbf, wt_tok, sca, nullptr, qkbf, vbuf);
  q2e_kernel<<<4096, blk, 0, stream>>>(qkbf, phi, pmax, q2buf, ebuf);
  flash_kernel<<<dim3(32, 32), blk, 0, stream>>>(qkbf, vbuf, q2buf, ebuf, wbuf);
  gemm_kernel<4, 64><<<dim3(64, 8), blk, 0, stream>>>(wbuf, wt_out, agv, x, out, nullptr);

  // --- channel attention ---
  ln_mod_kernel<<<4096, blk, 0, stream>>>(out, n2s, n2b, cvec, nullptr, nullptr, xbf);
  gemm_kernel<11, 128><<<dim3(32, 16), blk, 0, stream>>>(xbf, wt_ch, scc, nullptr, qkbf, vbuf);
  gram_kernel<<<dim3(16, 8), blk, 0, stream>>>(qkbf, dotp);
  chsm_kernel<<<2048, dim3(128), 0, stream>>>(dotp, tau, attnc);
  chav_kernel<<<dim3(32, 16), blk, 0, stream>>>(attnc, vbuf, wbuf);
  gemm_kernel<4, 64><<<dim3(64, 8), blk, 0, stream>>>(wbuf, wt_cout, cgv, out, out, nullptr);
}